// Round 1
// baseline (131.249 us; speedup 1.0000x reference)
//
#include <hip/hip_runtime.h>

#define RES 128
#define FEAT 16
#define NQ 1000000

__device__ __forceinline__ void fma4(float4& a, float w, const float4& f) {
    a.x = fmaf(w, f.x, a.x);
    a.y = fmaf(w, f.y, a.y);
    a.z = fmaf(w, f.z, a.z);
    a.w = fmaf(w, f.w, a.w);
}

__global__ __launch_bounds__(256) void tetra_interp_kernel(
    const float* __restrict__ xyz,
    const float* __restrict__ field,
    float* __restrict__ out)
{
    int q = blockIdx.x * blockDim.x + threadIdx.x;
    if (q >= NQ) return;

    float x = xyz[q * 3 + 0];
    float y = xyz[q * 3 + 1];
    float z = xyz[q * 3 + 2];

    const float scale = 127.0f;        // RES - 1
    const float h = 1.0f / 127.0f;     // grid spacing

    int cx = (int)floorf(x * scale); cx = min(max(cx, 0), RES - 2);
    int cy = (int)floorf(y * scale); cy = min(max(cy, 0), RES - 2);
    int cz = (int)floorf(z * scale); cz = min(max(cz, 0), RES - 2);

    // t = (x - lo) / (hi - lo), lo = cx*h, hi-lo = h
    float tx = (x - (float)cx * h) * scale;
    float ty = (y - (float)cy * h) * scale;
    float tz = (z - (float)cz * h) * scale;

    float wx0 = 1.0f - tx, wx1 = tx;
    float wy0 = 1.0f - ty, wy1 = ty;
    float wz0 = 1.0f - tz, wz1 = tz;

    // weight order matches vid order: bit pattern c = 4*ix + 2*iy + iz
    float w[8] = {
        wx0 * wy0 * wz0, wx0 * wy0 * wz1,
        wx0 * wy1 * wz0, wx0 * wy1 * wz1,
        wx1 * wy0 * wz0, wx1 * wy0 * wz1,
        wx1 * wy1 * wz0, wx1 * wy1 * wz1
    };

    long long base = ((long long)cx * RES + cy) * RES + cz;
    const long long R2 = (long long)RES * RES;
    const long long offs[8] = { 0, 1, RES, RES + 1, R2, R2 + 1, R2 + RES, R2 + RES + 1 };

    float4 acc0 = make_float4(0.f, 0.f, 0.f, 0.f);
    float4 acc1 = acc0, acc2 = acc0, acc3 = acc0;

#pragma unroll
    for (int c = 0; c < 8; ++c) {
        const float4* p = (const float4*)(field + (base + offs[c]) * FEAT);
        float4 f0 = p[0];
        float4 f1 = p[1];
        float4 f2 = p[2];
        float4 f3 = p[3];
        float wc = w[c];
        fma4(acc0, wc, f0);
        fma4(acc1, wc, f1);
        fma4(acc2, wc, f2);
        fma4(acc3, wc, f3);
    }

    float4* o = (float4*)(out + (long long)q * FEAT);
    o[0] = acc0;
    o[1] = acc1;
    o[2] = acc2;
    o[3] = acc3;
}

extern "C" void kernel_launch(void* const* d_in, const int* in_sizes, int n_in,
                              void* d_out, int out_size, void* d_ws, size_t ws_size,
                              hipStream_t stream) {
    const float* xyz   = (const float*)d_in[0];
    const float* field = (const float*)d_in[1];
    // d_in[2] = grid_xyz (uniform linspace — recomputed analytically)
    // d_in[3] = neighbor_index (offsets are fixed constants, never -1 in range)
    float* out = (float*)d_out;

    int blocks = (NQ + 255) / 256;
    tetra_interp_kernel<<<blocks, 256, 0, stream>>>(xyz, field, out);
}